// Round 6
// baseline (378.758 us; speedup 1.0000x reference)
//
#include <hip/hip_runtime.h>
#include <hip/hip_bf16.h>

typedef short short8 __attribute__((ext_vector_type(8)));
typedef float f32x4 __attribute__((ext_vector_type(4)));

// ---------- helpers ----------
static __device__ __forceinline__ float bf2f(unsigned int b) { return __uint_as_float(b << 16); }
static __device__ __forceinline__ short fb2s(float x) {       // f32 -> bf16 (RNE, for prepack)
    unsigned u = __float_as_uint(x);
    return (short)((u + 0x7FFFu + ((u >> 16) & 1u)) >> 16);
}
// pack two f32 -> bf16x2 in one instruction (RNE)
static __device__ __forceinline__ unsigned int pack2(float lo, float hi) {
    unsigned int r;
    asm("v_cvt_pk_bf16_f32 %0, %1, %2" : "=v"(r) : "v"(lo), "v"(hi));
    return r;
}
// scaled silu: input y = 1.4427*x, returns 1.4427*silu(x) = y*rcp(1+2^-y)
// (the 1.4427 factors are folded into the prepacked weights)
static __device__ __forceinline__ float hsilu(float y) {
    return y * __builtin_amdgcn_rcpf(1.0f + __builtin_amdgcn_exp2f(-y));
}
static __device__ __forceinline__ float load1(const void* p, long off, int isbf) {
    return isbf ? bf2f(((const unsigned short*)p)[off]) : ((const float*)p)[off];
}
static __device__ __forceinline__ void load4(const void* p, long off, int isbf, float* o) {
    if (isbf) {
        uint2 v = *(const uint2*)((const unsigned short*)p + off);
        o[0]=bf2f(v.x&0xffffu); o[1]=bf2f(v.x>>16);
        o[2]=bf2f(v.y&0xffffu); o[3]=bf2f(v.y>>16);
    } else {
        float4 v = *(const float4*)((const float*)p + off);
        o[0]=v.x; o[1]=v.y; o[2]=v.z; o[3]=v.w;
    }
}
// per-wave dtype detection (deterministic, wave-uniform; no barrier needed)
static __device__ __forceinline__ int detect_bf16(const void* nf) {
    const unsigned int* w = (const unsigned int*)nf;
    int lane = threadIdx.x & 63;
    unsigned int e = (w[lane] >> 7) & 0xFFu;
    unsigned long long m = __ballot(e >= 118u && e <= 132u);
    return __popcll(m) >= 32 ? 1 : 0;
}

// ---------- fused kernel: prepack (blocks 0..43) + acc zero + per-node projections ----------
#define NB 32
__global__ __launch_bounds__(256) void k_node(
    const void* __restrict__ nf, const void* __restrict__ W0, const void* __restrict__ W1,
    const void* __restrict__ w1, const void* __restrict__ w2,
    const void* __restrict__ w3, const void* __restrict__ w4,
    short* __restrict__ Bws, float* __restrict__ NA, float* __restrict__ acc, int n_nodes) {
    __shared__ float Nd0[NB * 68];
    __shared__ float Nd1[3 * NB * 68];
    __shared__ float W0L[8 * 68];
    __shared__ float W1L[8 * 68];
    const int tid = threadIdx.x;
    const int isbf = detect_bf16(nf);
    const long n0 = (long)blockIdx.x * NB;

    // --- prepack MLP weights into MFMA fragment layout (first 44 blocks) ---
    // Fragment element (lane, j) = W[k = (lane>>4)*8+j][n = (lane&15)+tile*16];
    // simultaneously B-frag of W and A-frag of W^T (operand-swap safe).
    // exp2-fold: W1 carries an extra log2(e); layers 2/3 unchanged (factors cancel);
    // W4 carries ln2 to remove it.
    if (blockIdx.x < 44) {
        int idx = blockIdx.x * 256 + tid;
        int j = idx & 7, lane = (idx >> 3) & 63, tile = idx >> 9;
        int n16 = lane & 15, kq = lane >> 4;
        float v;
        if (tile < 4) {
            int k = kq * 8 + j, n = tile * 16 + n16;
            v = (k < 8) ? load1(w1, k * 64 + n, isbf) * (0.35355339059327373f * 1.4426950408889634f) : 0.0f;
        } else if (tile < 12) {
            int t = (tile - 4) >> 1, kt = (tile - 4) & 1;
            int k = kt * 32 + kq * 8 + j, n = t * 16 + n16;
            v = load1(w2, k * 64 + n, isbf) * 0.125f;
        } else if (tile < 20) {
            int t = (tile - 12) >> 1, kt = (tile - 12) & 1;
            int k = kt * 32 + kq * 8 + j, n = t * 16 + n16;
            v = load1(w3, k * 64 + n, isbf) * 0.125f;
        } else {
            int kt = tile - 20;
            int k = kt * 32 + kq * 8 + j, n = n16;
            v = load1(w4, k * 16 + n, isbf) * (0.125f * 0.6931471805599453f);
        }
        Bws[idx] = fb2s(v);
    }
    // --- zero the edge accumulator ---
    if (tid < NB) {
        long n = n0 + tid;
        if (n < n_nodes) acc[n] = 0.0f;
    }
    if (n0 >= n_nodes) return;   // pure-prepack block (grid = max(nblk,44))

    // --- stage node_feats ---
    for (int i = tid; i < 512; i += 256) {
        W0L[(i >> 6) * 68 + (i & 63)] = load1(W0, i, isbf);
        W1L[(i >> 6) * 68 + (i & 63)] = load1(W1, i, isbf);
    }
    if (isbf) {
        for (int i = tid; i < NB * 32; i += 256) {
            int node = i >> 5, c8 = (i & 31) * 8;
            long ng = n0 + node; if (ng > n_nodes - 1) ng = n_nodes - 1;
            uint4 v = *(const uint4*)((const unsigned short*)nf + ng * 256 + c8);
            float f[8];
            f[0]=bf2f(v.x&0xffffu); f[1]=bf2f(v.x>>16);
            f[2]=bf2f(v.y&0xffffu); f[3]=bf2f(v.y>>16);
            f[4]=bf2f(v.z&0xffffu); f[5]=bf2f(v.z>>16);
            f[6]=bf2f(v.w&0xffffu); f[7]=bf2f(v.w>>16);
            #pragma unroll
            for (int t = 0; t < 8; t++) {
                int col = c8 + t;
                if (col < 64) Nd0[node * 68 + col] = f[t];
                else {
                    int cc = col - 64, vv = cc / 3, kk = cc - vv * 3;
                    Nd1[(kk * NB + node) * 68 + vv] = f[t];
                }
            }
        }
    } else {
        for (int i = tid; i < NB * 64; i += 256) {
            int node = i >> 6, c4 = (i & 63) * 4;
            long ng = n0 + node; if (ng > n_nodes - 1) ng = n_nodes - 1;
            float4 v = *(const float4*)((const float*)nf + ng * 256 + c4);
            float f[4] = {v.x, v.y, v.z, v.w};
            #pragma unroll
            for (int t = 0; t < 4; t++) {
                int col = c4 + t;
                if (col < 64) Nd0[node * 68 + col] = f[t];
                else {
                    int cc = col - 64, vv = cc / 3, kk = cc - vv * 3;
                    Nd1[(kk * NB + node) * 68 + vv] = f[t];
                }
            }
        }
    }
    __syncthreads();

    const int wv = tid >> 6, lane = tid & 63;
    const int u = lane & 7, ln = lane >> 3;
    float sum[4] = {0.0f, 0.0f, 0.0f, 0.0f};

    if (wv == 0) {
        const float* w = &W0L[u * 68];
        for (int v0 = 0; v0 < 64; v0 += 4) {
            float4 w4 = *(const float4*)(w + v0);
            #pragma unroll
            for (int j = 0; j < 4; j++) {
                float4 nd = *(const float4*)&Nd0[(ln + 8 * j) * 68 + v0];
                sum[j] += w4.x * nd.x + w4.y * nd.y + w4.z * nd.z + w4.w * nd.w;
            }
        }
        #pragma unroll
        for (int j = 0; j < 4; j++) {
            long node = n0 + ln + 8 * j;
            if (node < n_nodes) NA[node * 32 + u] = sum[j] * 0.03125f;
        }
    } else {
        const int kk = wv - 1;
        const float* w = &W1L[u * 68];
        const float* nd1 = &Nd1[kk * NB * 68];
        for (int v0 = 0; v0 < 64; v0 += 4) {
            float4 w4 = *(const float4*)(w + v0);
            #pragma unroll
            for (int j = 0; j < 4; j++) {
                float4 nd = *(const float4*)&nd1[(ln + 8 * j) * 68 + v0];
                sum[j] += w4.x * nd.x + w4.y * nd.y + w4.z * nd.z + w4.w * nd.w;
            }
        }
        #pragma unroll
        for (int j = 0; j < 4; j++) {
            long node = n0 + ln + 8 * j;
            if (node < n_nodes) NA[node * 32 + 8 + u * 3 + kk] = sum[j] * 0.018042195912175804f;
        }
    }
}

// ---------- MFMA edge kernel (operand-swapped: D = W^T @ H^T), 32 edges/wave ----------
// R2-proven structure: W in LDS (22 ds_read_b128 amortized over 32 edges via mt=0,1),
// + exp2-fold silu + fully in-register epilogue (no TP LDS round-trip).
// H layout (per wave, 32 rows x 72 shorts): physical short idx =
//   row*72 + ((col>>3) ^ ((row>>3)&1))*8 + (col&7);  row = edge-in-tile, col = feature.
// Read  (B-frag of H^T): lane(n16,kq) reads row=mt*16+n16, cols kt*32+kq*8..+7 -> b128.
// Write (D of Y^T):      lane(n16,kq) writes row=mt*16+n16, cols t*16+kq*4..+3 -> b64.
// Epilogue: after L4, lane(n16,kq) holds feats kq*4..+3 of edge mt*16+n16;
// partial dot per lane, shfl_xor(16)+shfl_xor(32) reduce over kq, kq==0 atomics.
__global__ __launch_bounds__(256, 4) void k_edges_mfma(
    const void* __restrict__ ef, const void* __restrict__ ea, const void* __restrict__ qc,
    const int* __restrict__ eidx, const void* __restrict__ nf,
    const short* __restrict__ Bws, const float* __restrict__ NA,
    float* __restrict__ acc, int n_edges) {
    __shared__ __align__(16) short W[11264];
    __shared__ __align__(16) short Hs[4 * 2304];
    const int tid = threadIdx.x, lane = tid & 63, wv = tid >> 6;
    const int n16 = lane & 15, kq = lane >> 4;
    const int isbf = detect_bf16(nf);

    {
        const uint4* src = (const uint4*)Bws;
        uint4* dst = (uint4*)W;
        for (int i = tid; i < 1408; i += 256) dst[i] = src[i];
    }
    __syncthreads();

    short* Hw = Hs + wv * 2304;
    const int rbit = (n16 >> 3) & 1;                 // swizzle bit (shared by reads+writes)
    const int wrow = n16 * 72 + ((kq & 1) << 2);     // per-lane write base within a row
    const int kql = (kq & 1) << 2;                   // q-feature offset for epilogue
    const f32x4 zero = {0.0f, 0.0f, 0.0f, 0.0f};

    for (int half = 0; half < 2; half++) {
        const long E0 = (long)blockIdx.x * 256 + half * 128 + wv * 32;

        // ---- phase-1 gathers: edge-indexed (per mt; this lane's edge = E0+mt*16+n16) ----
        long e_[2]; long ec_[2]; int s_[2], r_[2]; float eav_[2][4];
        #pragma unroll
        for (int mt = 0; mt < 2; mt++) {
            e_[mt] = E0 + mt * 16 + n16;
            long ec = e_[mt]; if (ec > n_edges - 1) ec = n_edges - 1;
            ec_[mt] = ec;
            s_[mt] = eidx[ec];
            r_[mt] = eidx[(long)n_edges + ec];
            load4(ea, ec * 4, isbf, eav_[mt]);
        }

        // ---- layer-1 B operand: edge_feats^T fragments ----
        short8 a1[2];
        #pragma unroll
        for (int mt = 0; mt < 2; mt++) {
            short8 a = {0,0,0,0,0,0,0,0};
            if (kq == 0) {
                if (isbf) {
                    a = *(const short8*)((const unsigned short*)ef + ec_[mt] * 8);
                } else {
                    const float* pe = (const float*)ef + ec_[mt] * 8;
                    float4 v0 = *(const float4*)pe, v1 = *(const float4*)(pe + 4);
                    a[0]=fb2s(v0.x); a[1]=fb2s(v0.y); a[2]=fb2s(v0.z); a[3]=fb2s(v0.w);
                    a[4]=fb2s(v1.x); a[5]=fb2s(v1.y); a[6]=fb2s(v1.z); a[7]=fb2s(v1.w);
                }
            }
            a1[mt] = a;
        }

        {   // layer 1: Y^T[feat][edge] = W1^T @ X^T
            f32x4 c1[2][4];
            #pragma unroll
            for (int t = 0; t < 4; t++) {
                short8 b = *(const short8*)(W + t * 512 + lane * 8);
                #pragma unroll
                for (int mt = 0; mt < 2; mt++)
                    c1[mt][t] = __builtin_amdgcn_mfma_f32_16x16x32_bf16(b, a1[mt], zero, 0, 0, 0);
            }
            #pragma unroll
            for (int mt = 0; mt < 2; mt++)
                #pragma unroll
                for (int t = 0; t < 4; t++) {
                    uint2 pkd;
                    pkd.x = pack2(hsilu(c1[mt][t][0]), hsilu(c1[mt][t][1]));
                    pkd.y = pack2(hsilu(c1[mt][t][2]), hsilu(c1[mt][t][3]));
                    *(uint2*)(Hw + mt * 1152 + wrow + (((t * 2 + (kq >> 1)) ^ rbit) << 3)) = pkd;
                }
        }

        // ---- phase-2 gathers: node-indexed, hide under layers 2-4 ----
        float q4_[2][4], na_[2][12];
        #pragma unroll
        for (int mt = 0; mt < 2; mt++) {
            load4(qc, (long)s_[mt] * 8 + kql, isbf, q4_[mt]);
            const float* nr = NA + (long)r_[mt] * 32;
            if (kq < 2) {
                *(float4*)na_[mt] = *(const float4*)(nr + (kq << 2));
            } else {
                *(float4*)(na_[mt] + 0) = *(const float4*)(nr + 8 + (kq - 2) * 12);
                *(float4*)(na_[mt] + 4) = *(const float4*)(nr + 12 + (kq - 2) * 12);
                *(float4*)(na_[mt] + 8) = *(const float4*)(nr + 16 + (kq - 2) * 12);
            }
        }

        #pragma unroll
        for (int L = 0; L < 2; L++) {   // layers 2,3: Y^T = W^T(64x64) @ H^T
            const int base = (L == 0) ? 4 : 12;
            short8 aH[2][2];
            #pragma unroll
            for (int mt = 0; mt < 2; mt++)
                #pragma unroll
                for (int kt = 0; kt < 2; kt++)
                    aH[mt][kt] = *(const short8*)(Hw + mt * 1152 + n16 * 72 + (((kt * 4 + kq) ^ rbit) << 3));
            f32x4 c2[2][4];
            #pragma unroll
            for (int mt = 0; mt < 2; mt++)
                #pragma unroll
                for (int t = 0; t < 4; t++) c2[mt][t] = zero;
            #pragma unroll
            for (int kt = 0; kt < 2; kt++)
                #pragma unroll
                for (int t = 0; t < 4; t++) {
                    short8 b = *(const short8*)(W + (base + t * 2 + kt) * 512 + lane * 8);
                    #pragma unroll
                    for (int mt = 0; mt < 2; mt++)
                        c2[mt][t] = __builtin_amdgcn_mfma_f32_16x16x32_bf16(b, aH[mt][kt], c2[mt][t], 0, 0, 0);
                }
            #pragma unroll
            for (int mt = 0; mt < 2; mt++)
                #pragma unroll
                for (int t = 0; t < 4; t++) {
                    uint2 pkd;
                    pkd.x = pack2(hsilu(c2[mt][t][0]), hsilu(c2[mt][t][1]));
                    pkd.y = pack2(hsilu(c2[mt][t][2]), hsilu(c2[mt][t][3]));
                    *(uint2*)(Hw + mt * 1152 + wrow + (((t * 2 + (kq >> 1)) ^ rbit) << 3)) = pkd;
                }
        }

        f32x4 c4[2] = {zero, zero};
        {   // layer 4: 16 outputs per edge
            short8 aH[2][2];
            #pragma unroll
            for (int mt = 0; mt < 2; mt++)
                #pragma unroll
                for (int kt = 0; kt < 2; kt++)
                    aH[mt][kt] = *(const short8*)(Hw + mt * 1152 + n16 * 72 + (((kt * 4 + kq) ^ rbit) << 3));
            #pragma unroll
            for (int kt = 0; kt < 2; kt++) {
                short8 b = *(const short8*)(W + (20 + kt) * 512 + lane * 8);
                #pragma unroll
                for (int mt = 0; mt < 2; mt++)
                    c4[mt] = __builtin_amdgcn_mfma_f32_16x16x32_bf16(b, aH[mt][kt], c4[mt], 0, 0, 0);
            }
        }

        // ---- epilogue in-register: lane holds feats kq*4..+3 of edge mt*16+n16 ----
        #pragma unroll
        for (int mt = 0; mt < 2; mt++) {
            float p = 0.0f;
            if (kq < 2) {
                #pragma unroll
                for (int r = 0; r < 4; r++) p += c4[mt][r] * q4_[mt][r] * na_[mt][r];
                p *= eav_[mt][0];
            } else {
                #pragma unroll
                for (int r = 0; r < 4; r++) {
                    float d = eav_[mt][1] * na_[mt][r * 3] + eav_[mt][2] * na_[mt][r * 3 + 1]
                            + eav_[mt][3] * na_[mt][r * 3 + 2];
                    p += c4[mt][r] * q4_[mt][r] * d;
                }
            }
            p += __shfl_xor(p, 16);
            p += __shfl_xor(p, 32);
            if (kq == 0 && e_[mt] < n_edges) atomicAdd(&acc[r_[mt]], p);
        }
    }
}

// ---------- accumulator -> output ----------
__global__ void k_out(const float* __restrict__ acc, void* __restrict__ out,
                      const void* __restrict__ nf, int n) {
    const int isbf = detect_bf16(nf);
    int i = blockIdx.x * 256 + threadIdx.x;
    if (i >= n) return;
    if (isbf) ((__hip_bfloat16*)out)[i] = __float2bfloat16(acc[i]);
    else      ((float*)out)[i] = acc[i];
}

// ---------- launch ----------
extern "C" void kernel_launch(void* const* d_in, const int* in_sizes, int n_in,
                              void* d_out, int out_size, void* d_ws, size_t ws_size,
                              hipStream_t stream) {
    const void* node_feats      = d_in[0];
    const void* charges_induced = d_in[2];
    const void* edge_feats      = d_in[3];
    const void* edge_attrs      = d_in[4];
    const void* mlp_w1          = d_in[6];
    const void* mlp_w2          = d_in[7];
    const void* mlp_w3          = d_in[8];
    const void* mlp_w4          = d_in[9];
    const void* W0              = d_in[10];
    const void* W1              = d_in[11];
    const int*  edge_index      = (const int*)d_in[12];

    const int n_nodes = in_sizes[0] / 256;
    const int n_edges = in_sizes[3] / 8;

    short* Bws = (short*)d_ws;                                 // 11264 shorts
    float* NA  = (float*)((char*)d_ws + 22528);                // n_nodes*32 f32
    float* acc = NA + (size_t)n_nodes * 32;                    // n_nodes f32

    int nblk = (n_nodes + NB - 1) / NB;
    if (nblk < 44) nblk = 44;
    k_node<<<nblk, 256, 0, stream>>>(node_feats, W0, W1,
        mlp_w1, mlp_w2, mlp_w3, mlp_w4, Bws, NA, acc, n_nodes);
    k_edges_mfma<<<(n_edges + 255) / 256, 256, 0, stream>>>(
        edge_feats, edge_attrs, charges_induced, edge_index, node_feats, Bws, NA, acc, n_edges);
    k_out<<<(n_nodes + 255) / 256, 256, 0, stream>>>(acc, d_out, node_feats, n_nodes);
}

// Round 7
// 355.006 us; speedup vs baseline: 1.0669x; 1.0669x over previous
//
#include <hip/hip_runtime.h>
#include <hip/hip_bf16.h>

typedef short short8 __attribute__((ext_vector_type(8)));
typedef float f32x4 __attribute__((ext_vector_type(4)));
typedef unsigned int u32x4 __attribute__((ext_vector_type(4)));

// ---------- helpers ----------
static __device__ __forceinline__ float bf2f(unsigned int b) { return __uint_as_float(b << 16); }
static __device__ __forceinline__ short fb2s(float x) {       // f32 -> bf16 (RNE, for prepack)
    unsigned u = __float_as_uint(x);
    return (short)((u + 0x7FFFu + ((u >> 16) & 1u)) >> 16);
}
// pack two f32 -> bf16x2 in one instruction (RNE)
static __device__ __forceinline__ unsigned int pack2(float lo, float hi) {
    unsigned int r;
    asm("v_cvt_pk_bf16_f32 %0, %1, %2" : "=v"(r) : "v"(lo), "v"(hi));
    return r;
}
// scaled silu: input y = 1.4427*x, returns 1.4427*silu(x) = y*rcp(1+2^-y)
static __device__ __forceinline__ float hsilu(float y) {
    return y * __builtin_amdgcn_rcpf(1.0f + __builtin_amdgcn_exp2f(-y));
}
static __device__ __forceinline__ float load1(const void* p, long off, int isbf) {
    return isbf ? bf2f(((const unsigned short*)p)[off]) : ((const float*)p)[off];
}
static __device__ __forceinline__ void load4(const void* p, long off, int isbf, float* o) {
    if (isbf) {
        uint2 v = *(const uint2*)((const unsigned short*)p + off);
        o[0]=bf2f(v.x&0xffffu); o[1]=bf2f(v.x>>16);
        o[2]=bf2f(v.y&0xffffu); o[3]=bf2f(v.y>>16);
    } else {
        float4 v = *(const float4*)((const float*)p + off);
        o[0]=v.x; o[1]=v.y; o[2]=v.z; o[3]=v.w;
    }
}
static __device__ __forceinline__ int detect_bf16(const void* nf) {
    const unsigned int* w = (const unsigned int*)nf;
    int lane = threadIdx.x & 63;
    unsigned int e = (w[lane] >> 7) & 0xFFu;
    unsigned long long m = __ballot(e >= 118u && e <= 132u);
    return __popcll(m) >= 32 ? 1 : 0;
}
static __device__ __forceinline__ short8 u4_to_s8(u32x4 u) {
    union { u32x4 u; short8 s; } cvt; cvt.u = u; return cvt.s;
}

// Feat permutation for hidden layers: tile t' row rr produces ORIGINAL feat F(t',rr).
// Chosen so the inter-layer fragment redistribution is a pure kq-rotation:
// dest pair q[kt][j2] = p[2kt+(j2&1)][j2>>1] pulled from lane (l - 16*t') mod 64.
static __device__ __forceinline__ int Fmap(int tp, int rr) {
    int kq_s = rr >> 2, h = (rr >> 1) & 1, b = rr & 1;
    return 32 * (tp >> 1) + 8 * ((kq_s + tp) & 3) + 2 * (2 * h + (tp & 1)) + b;
}

// ---------- fused kernel: prepack (blocks 0..43) + acc zero + per-node projections ----------
#define NB 32
__global__ __launch_bounds__(256) void k_node(
    const void* __restrict__ nf, const void* __restrict__ W0, const void* __restrict__ W1,
    const void* __restrict__ w1, const void* __restrict__ w2,
    const void* __restrict__ w3, const void* __restrict__ w4,
    short* __restrict__ Bws, float* __restrict__ NA, float* __restrict__ acc, int n_nodes) {
    __shared__ float Nd0[NB * 68];
    __shared__ float Nd1[3 * NB * 68];
    __shared__ float W0L[8 * 68];
    __shared__ float W1L[8 * 68];
    const int tid = threadIdx.x;
    const int isbf = detect_bf16(nf);
    const long n0 = (long)blockIdx.x * NB;

    // --- prepack MLP weights into MFMA fragment layout (first 44 blocks) ---
    // Fragment element (lane, j) = W[k = (lane>>4)*8+j][n]; n = Fmap(t', lane&15) for
    // hidden-layer outputs (w1,w2,w3), n = lane&15 for w4 (standard).
    // exp2-fold: W1 carries log2(e); W4 carries ln2 to cancel it.
    if (blockIdx.x < 44) {
        int idx = blockIdx.x * 256 + tid;
        int j = idx & 7, lane = (idx >> 3) & 63, tile = idx >> 9;
        int n16 = lane & 15, kq = lane >> 4;
        float v;
        if (tile < 4) {
            int k = kq * 8 + j, n = Fmap(tile, n16);
            v = (k < 8) ? load1(w1, k * 64 + n, isbf) * (0.35355339059327373f * 1.4426950408889634f) : 0.0f;
        } else if (tile < 12) {
            int t = (tile - 4) >> 1, kt = (tile - 4) & 1;
            int k = kt * 32 + kq * 8 + j, n = Fmap(t, n16);
            v = load1(w2, k * 64 + n, isbf) * 0.125f;
        } else if (tile < 20) {
            int t = (tile - 12) >> 1, kt = (tile - 12) & 1;
            int k = kt * 32 + kq * 8 + j, n = Fmap(t, n16);
            v = load1(w3, k * 64 + n, isbf) * 0.125f;
        } else {
            int kt = tile - 20;
            int k = kt * 32 + kq * 8 + j, n = n16;
            v = load1(w4, k * 16 + n, isbf) * (0.125f * 0.6931471805599453f);
        }
        Bws[idx] = fb2s(v);
    }
    // --- zero the edge accumulator ---
    if (tid < NB) {
        long n = n0 + tid;
        if (n < n_nodes) acc[n] = 0.0f;
    }
    if (n0 >= n_nodes) return;   // pure-prepack block (grid = max(nblk,44))

    // --- stage node_feats ---
    for (int i = tid; i < 512; i += 256) {
        W0L[(i >> 6) * 68 + (i & 63)] = load1(W0, i, isbf);
        W1L[(i >> 6) * 68 + (i & 63)] = load1(W1, i, isbf);
    }
    if (isbf) {
        for (int i = tid; i < NB * 32; i += 256) {
            int node = i >> 5, c8 = (i & 31) * 8;
            long ng = n0 + node; if (ng > n_nodes - 1) ng = n_nodes - 1;
            uint4 v = *(const uint4*)((const unsigned short*)nf + ng * 256 + c8);
            float f[8];
            f[0]=bf2f(v.x&0xffffu); f[1]=bf2f(v.x>>16);
            f[2]=bf2f(v.y&0xffffu); f[3]=bf2f(v.y>>16);
            f[4]=bf2f(v.z&0xffffu); f[5]=bf2f(v.z>>16);
            f[6]=bf2f(v.w&0xffffu); f[7]=bf2f(v.w>>16);
            #pragma unroll
            for (int t = 0; t < 8; t++) {
                int col = c8 + t;
                if (col < 64) Nd0[node * 68 + col] = f[t];
                else {
                    int cc = col - 64, vv = cc / 3, kk = cc - vv * 3;
                    Nd1[(kk * NB + node) * 68 + vv] = f[t];
                }
            }
        }
    } else {
        for (int i = tid; i < NB * 64; i += 256) {
            int node = i >> 6, c4 = (i & 63) * 4;
            long ng = n0 + node; if (ng > n_nodes - 1) ng = n_nodes - 1;
            float4 v = *(const float4*)((const float*)nf + ng * 256 + c4);
            float f[4] = {v.x, v.y, v.z, v.w};
            #pragma unroll
            for (int t = 0; t < 4; t++) {
                int col = c4 + t;
                if (col < 64) Nd0[node * 68 + col] = f[t];
                else {
                    int cc = col - 64, vv = cc / 3, kk = cc - vv * 3;
                    Nd1[(kk * NB + node) * 68 + vv] = f[t];
                }
            }
        }
    }
    __syncthreads();

    const int wv = tid >> 6, lane = tid & 63;
    const int u = lane & 7, ln = lane >> 3;
    float sum[4] = {0.0f, 0.0f, 0.0f, 0.0f};

    if (wv == 0) {
        const float* w = &W0L[u * 68];
        for (int v0 = 0; v0 < 64; v0 += 4) {
            float4 w4 = *(const float4*)(w + v0);
            #pragma unroll
            for (int j = 0; j < 4; j++) {
                float4 nd = *(const float4*)&Nd0[(ln + 8 * j) * 68 + v0];
                sum[j] += w4.x * nd.x + w4.y * nd.y + w4.z * nd.z + w4.w * nd.w;
            }
        }
        #pragma unroll
        for (int j = 0; j < 4; j++) {
            long node = n0 + ln + 8 * j;
            if (node < n_nodes) NA[node * 32 + u] = sum[j] * 0.03125f;
        }
    } else {
        const int kk = wv - 1;
        const float* w = &W1L[u * 68];
        const float* nd1 = &Nd1[kk * NB * 68];
        for (int v0 = 0; v0 < 64; v0 += 4) {
            float4 w4 = *(const float4*)(w + v0);
            #pragma unroll
            for (int j = 0; j < 4; j++) {
                float4 nd = *(const float4*)&nd1[(ln + 8 * j) * 68 + v0];
                sum[j] += w4.x * nd.x + w4.y * nd.y + w4.z * nd.z + w4.w * nd.w;
            }
        }
        #pragma unroll
        for (int j = 0; j < 4; j++) {
            long node = n0 + ln + 8 * j;
            if (node < n_nodes) NA[node * 32 + 8 + u * 3 + kk] = sum[j] * 0.018042195912175804f;
        }
    }
}

// ---------- MFMA edge kernel: no H LDS — inter-layer redistribution via ds_bpermute ----------
// W in LDS (22528 B only). 32 edges/wave. After each hidden layer, lane(n16,kq_s)
// holds c[t'][r] = feat F(t', kq_s*4+r) of edge n16; pack to bf16 pairs p[t'][h]
// and pull the next layer's B-fragment with rotations: identity (t'=0) and
// ds_bpermute from lane (l - 16*t') mod 64 (t'=1,2,3).
__global__ __launch_bounds__(256, 4) void k_edges_mfma(
    const void* __restrict__ ef, const void* __restrict__ ea, const void* __restrict__ qc,
    const int* __restrict__ eidx, const void* __restrict__ nf,
    const short* __restrict__ Bws, const float* __restrict__ NA,
    float* __restrict__ acc, int n_edges) {
    __shared__ __align__(16) short W[11264];
    const int tid = threadIdx.x, lane = tid & 63, wv = tid >> 6;
    const int n16 = lane & 15, kq = lane >> 4;
    const int isbf = detect_bf16(nf);

    {
        const uint4* src = (const uint4*)Bws;
        uint4* dst = (uint4*)W;
        for (int i = tid; i < 1408; i += 256) dst[i] = src[i];
    }
    __syncthreads();

    // bpermute byte-addresses for kq-rotations (src lane = (l - 16t') & 63)
    const int A1 = ((lane - 16) & 63) << 2;
    const int A2 = ((lane - 32) & 63) << 2;
    const int A3 = ((lane - 48) & 63) << 2;
    const int kql = (kq & 1) << 2;                   // q-feature offset for epilogue
    const f32x4 zero = {0.0f, 0.0f, 0.0f, 0.0f};

    for (int half = 0; half < 2; half++) {
        const long E0 = (long)blockIdx.x * 256 + half * 128 + wv * 32;

        // ---- phase-1 gathers: edge-indexed (small state: s,r,eav per mt) ----
        int s_[2], r_[2]; float eav_[2][4];
        short8 a1[2];
        #pragma unroll
        for (int mt = 0; mt < 2; mt++) {
            long ec = E0 + mt * 16 + n16; if (ec > n_edges - 1) ec = n_edges - 1;
            s_[mt] = eidx[ec];
            r_[mt] = eidx[(long)n_edges + ec];
            load4(ea, ec * 4, isbf, eav_[mt]);
            short8 a = {0,0,0,0,0,0,0,0};
            if (kq == 0) {
                if (isbf) {
                    a = *(const short8*)((const unsigned short*)ef + ec * 8);
                } else {
                    const float* pe = (const float*)ef + ec * 8;
                    float4 v0 = *(const float4*)pe, v1 = *(const float4*)(pe + 4);
                    a[0]=fb2s(v0.x); a[1]=fb2s(v0.y); a[2]=fb2s(v0.z); a[3]=fb2s(v0.w);
                    a[4]=fb2s(v1.x); a[5]=fb2s(v1.y); a[6]=fb2s(v1.z); a[7]=fb2s(v1.w);
                }
            }
            a1[mt] = a;
        }

        f32x4 c[2][4];
        short8 aH[2][2];

        // ---- layer 1 ----
        #pragma unroll
        for (int t = 0; t < 4; t++) {
            short8 b = *(const short8*)(W + t * 512 + lane * 8);
            #pragma unroll
            for (int mt = 0; mt < 2; mt++)
                c[mt][t] = __builtin_amdgcn_mfma_f32_16x16x32_bf16(b, a1[mt], zero, 0, 0, 0);
        }
        #pragma unroll
        for (int mt = 0; mt < 2; mt++) {
            unsigned p00 = pack2(hsilu(c[mt][0][0]), hsilu(c[mt][0][1]));
            unsigned p01 = pack2(hsilu(c[mt][0][2]), hsilu(c[mt][0][3]));
            unsigned p10 = pack2(hsilu(c[mt][1][0]), hsilu(c[mt][1][1]));
            unsigned p11 = pack2(hsilu(c[mt][1][2]), hsilu(c[mt][1][3]));
            unsigned p20 = pack2(hsilu(c[mt][2][0]), hsilu(c[mt][2][1]));
            unsigned p21 = pack2(hsilu(c[mt][2][2]), hsilu(c[mt][2][3]));
            unsigned p30 = pack2(hsilu(c[mt][3][0]), hsilu(c[mt][3][1]));
            unsigned p31 = pack2(hsilu(c[mt][3][2]), hsilu(c[mt][3][3]));
            unsigned q01 = (unsigned)__builtin_amdgcn_ds_bpermute(A1, (int)p10);
            unsigned q03 = (unsigned)__builtin_amdgcn_ds_bpermute(A1, (int)p11);
            unsigned q10 = (unsigned)__builtin_amdgcn_ds_bpermute(A2, (int)p20);
            unsigned q12 = (unsigned)__builtin_amdgcn_ds_bpermute(A2, (int)p21);
            unsigned q11 = (unsigned)__builtin_amdgcn_ds_bpermute(A3, (int)p30);
            unsigned q13 = (unsigned)__builtin_amdgcn_ds_bpermute(A3, (int)p31);
            u32x4 u0 = {p00, q01, p01, q03};
            u32x4 u1 = {q10, q11, q12, q13};
            aH[mt][0] = u4_to_s8(u0);
            aH[mt][1] = u4_to_s8(u1);
        }

        // ---- layers 2,3 ----
        #pragma unroll
        for (int L = 0; L < 2; L++) {
            const int base = (L == 0) ? 4 : 12;
            #pragma unroll
            for (int mt = 0; mt < 2; mt++)
                #pragma unroll
                for (int t = 0; t < 4; t++) c[mt][t] = zero;
            #pragma unroll
            for (int kt = 0; kt < 2; kt++)
                #pragma unroll
                for (int t = 0; t < 4; t++) {
                    short8 b = *(const short8*)(W + (base + t * 2 + kt) * 512 + lane * 8);
                    #pragma unroll
                    for (int mt = 0; mt < 2; mt++)
                        c[mt][t] = __builtin_amdgcn_mfma_f32_16x16x32_bf16(b, aH[mt][kt], c[mt][t], 0, 0, 0);
                }
            #pragma unroll
            for (int mt = 0; mt < 2; mt++) {
                unsigned p00 = pack2(hsilu(c[mt][0][0]), hsilu(c[mt][0][1]));
                unsigned p01 = pack2(hsilu(c[mt][0][2]), hsilu(c[mt][0][3]));
                unsigned p10 = pack2(hsilu(c[mt][1][0]), hsilu(c[mt][1][1]));
                unsigned p11 = pack2(hsilu(c[mt][1][2]), hsilu(c[mt][1][3]));
                unsigned p20 = pack2(hsilu(c[mt][2][0]), hsilu(c[mt][2][1]));
                unsigned p21 = pack2(hsilu(c[mt][2][2]), hsilu(c[mt][2][3]));
                unsigned p30 = pack2(hsilu(c[mt][3][0]), hsilu(c[mt][3][1]));
                unsigned p31 = pack2(hsilu(c[mt][3][2]), hsilu(c[mt][3][3]));
                unsigned q01 = (unsigned)__builtin_amdgcn_ds_bpermute(A1, (int)p10);
                unsigned q03 = (unsigned)__builtin_amdgcn_ds_bpermute(A1, (int)p11);
                unsigned q10 = (unsigned)__builtin_amdgcn_ds_bpermute(A2, (int)p20);
                unsigned q12 = (unsigned)__builtin_amdgcn_ds_bpermute(A2, (int)p21);
                unsigned q11 = (unsigned)__builtin_amdgcn_ds_bpermute(A3, (int)p30);
                unsigned q13 = (unsigned)__builtin_amdgcn_ds_bpermute(A3, (int)p31);
                u32x4 u0 = {p00, q01, p01, q03};
                u32x4 u1 = {q10, q11, q12, q13};
                aH[mt][0] = u4_to_s8(u0);
                aH[mt][1] = u4_to_s8(u1);
            }
        }

        // ---- layer 4 ----
        f32x4 c4[2] = {zero, zero};
        #pragma unroll
        for (int kt = 0; kt < 2; kt++) {
            short8 b = *(const short8*)(W + (20 + kt) * 512 + lane * 8);
            #pragma unroll
            for (int mt = 0; mt < 2; mt++)
                c4[mt] = __builtin_amdgcn_mfma_f32_16x16x32_bf16(b, aH[mt][kt], c4[mt], 0, 0, 0);
        }

        // ---- epilogue per mt (gathers here: single-tile live range, no spill) ----
        #pragma unroll
        for (int mt = 0; mt < 2; mt++) {
            float q4[4];
            load4(qc, (long)s_[mt] * 8 + kql, isbf, q4);
            float na[12];
            const float* nr = NA + (long)r_[mt] * 32;
            if (kq < 2) {
                *(float4*)na = *(const float4*)(nr + (kq << 2));
            } else {
                *(float4*)(na + 0) = *(const float4*)(nr + 8 + (kq - 2) * 12);
                *(float4*)(na + 4) = *(const float4*)(nr + 12 + (kq - 2) * 12);
                *(float4*)(na + 8) = *(const float4*)(nr + 16 + (kq - 2) * 12);
            }
            float p = 0.0f;
            if (kq < 2) {
                #pragma unroll
                for (int r = 0; r < 4; r++) p += c4[mt][r] * q4[r] * na[r];
                p *= eav_[mt][0];
            } else {
                #pragma unroll
                for (int r = 0; r < 4; r++) {
                    float d = eav_[mt][1] * na[r * 3] + eav_[mt][2] * na[r * 3 + 1]
                            + eav_[mt][3] * na[r * 3 + 2];
                    p += c4[mt][r] * q4[r] * d;
                }
            }
            p += __shfl_xor(p, 16);
            p += __shfl_xor(p, 32);
            if (kq == 0 && (E0 + mt * 16 + n16) < n_edges) atomicAdd(&acc[r_[mt]], p);
        }
    }
}

// ---------- accumulator -> output ----------
__global__ void k_out(const float* __restrict__ acc, void* __restrict__ out,
                      const void* __restrict__ nf, int n) {
    const int isbf = detect_bf16(nf);
    int i = blockIdx.x * 256 + threadIdx.x;
    if (i >= n) return;
    if (isbf) ((__hip_bfloat16*)out)[i] = __float2bfloat16(acc[i]);
    else      ((float*)out)[i] = acc[i];
}

// ---------- launch ----------
extern "C" void kernel_launch(void* const* d_in, const int* in_sizes, int n_in,
                              void* d_out, int out_size, void* d_ws, size_t ws_size,
                              hipStream_t stream) {
    const void* node_feats      = d_in[0];
    const void* charges_induced = d_in[2];
    const void* edge_feats      = d_in[3];
    const void* edge_attrs      = d_in[4];
    const void* mlp_w1          = d_in[6];
    const void* mlp_w2          = d_in[7];
    const void* mlp_w3          = d_in[8];
    const void* mlp_w4          = d_in[9];
    const void* W0              = d_in[10];
    const void* W1              = d_in[11];
    const int*  edge_index      = (const int*)d_in[12];

    const int n_nodes = in_sizes[0] / 256;
    const int n_edges = in_sizes[3] / 8;

    short* Bws = (short*)d_ws;                                 // 11264 shorts
    float* NA  = (float*)((char*)d_ws + 22528);                // n_nodes*32 f32
    float* acc = NA + (size_t)n_nodes * 32;                    // n_nodes f32

    int nblk = (n_nodes + NB - 1) / NB;
    if (nblk < 44) nblk = 44;
    k_node<<<nblk, 256, 0, stream>>>(node_feats, W0, W1,
        mlp_w1, mlp_w2, mlp_w3, mlp_w4, Bws, NA, acc, n_nodes);
    k_edges_mfma<<<(n_edges + 255) / 256, 256, 0, stream>>>(
        edge_feats, edge_attrs, charges_induced, edge_index, node_feats, Bws, NA, acc, n_edges);
    k_out<<<(n_nodes + 255) / 256, 256, 0, stream>>>(acc, d_out, node_feats, n_nodes);
}

// Round 8
// 311.526 us; speedup vs baseline: 1.2158x; 1.1396x over previous
//
#include <hip/hip_runtime.h>
#include <hip/hip_bf16.h>

typedef short short8 __attribute__((ext_vector_type(8)));
typedef float f32x4 __attribute__((ext_vector_type(4)));

// ---------- helpers ----------
static __device__ __forceinline__ float bf2f(unsigned int b) { return __uint_as_float(b << 16); }
static __device__ __forceinline__ short fb2s(float x) {       // f32 -> bf16 (RNE, for prepack)
    unsigned u = __float_as_uint(x);
    return (short)((u + 0x7FFFu + ((u >> 16) & 1u)) >> 16);
}
// pack two f32 -> bf16x2 in one instruction (RNE)
static __device__ __forceinline__ unsigned int pack2(float lo, float hi) {
    unsigned int r;
    asm("v_cvt_pk_bf16_f32 %0, %1, %2" : "=v"(r) : "v"(lo), "v"(hi));
    return r;
}
// scaled silu: input y = 1.4427*x, returns 1.4427*silu(x) = y*rcp(1+2^-y)
// (the log2(e) factor is folded into the prepacked weights; w4 carries ln2 to cancel)
static __device__ __forceinline__ float hsilu(float y) {
    return y * __builtin_amdgcn_rcpf(1.0f + __builtin_amdgcn_exp2f(-y));
}
static __device__ __forceinline__ float load1(const void* p, long off, int isbf) {
    return isbf ? bf2f(((const unsigned short*)p)[off]) : ((const float*)p)[off];
}
static __device__ __forceinline__ void load4(const void* p, long off, int isbf, float* o) {
    if (isbf) {
        uint2 v = *(const uint2*)((const unsigned short*)p + off);
        o[0]=bf2f(v.x&0xffffu); o[1]=bf2f(v.x>>16);
        o[2]=bf2f(v.y&0xffffu); o[3]=bf2f(v.y>>16);
    } else {
        float4 v = *(const float4*)((const float*)p + off);
        o[0]=v.x; o[1]=v.y; o[2]=v.z; o[3]=v.w;
    }
}
// per-wave dtype detection (deterministic, wave-uniform; no barrier needed)
static __device__ __forceinline__ int detect_bf16(const void* nf) {
    const unsigned int* w = (const unsigned int*)nf;
    int lane = threadIdx.x & 63;
    unsigned int e = (w[lane] >> 7) & 0xFFu;
    unsigned long long m = __ballot(e >= 118u && e <= 132u);
    return __popcll(m) >= 32 ? 1 : 0;
}

// ---------- fused kernel: prepack (blocks 0..43) + acc zero + per-node projections ----------
#define NB 32
__global__ __launch_bounds__(256) void k_node(
    const void* __restrict__ nf, const void* __restrict__ W0, const void* __restrict__ W1,
    const void* __restrict__ w1, const void* __restrict__ w2,
    const void* __restrict__ w3, const void* __restrict__ w4,
    short* __restrict__ Bws, float* __restrict__ NA, float* __restrict__ acc, int n_nodes) {
    __shared__ float Nd0[NB * 68];
    __shared__ float Nd1[3 * NB * 68];
    __shared__ float W0L[8 * 68];
    __shared__ float W1L[8 * 68];
    const int tid = threadIdx.x;
    const int isbf = detect_bf16(nf);
    const long n0 = (long)blockIdx.x * NB;

    // --- prepack MLP weights into MFMA fragment layout (first 44 blocks) ---
    // Fragment element (lane, j) = W[k = (lane>>4)*8+j][n = (lane&15)+tile*16];
    // simultaneously B-frag of W and A-frag of W^T (operand-swap safe).
    // exp2-fold: W1 carries an extra log2(e); layers 2/3 unchanged (factors cancel);
    // W4 carries ln2 to remove it.
    if (blockIdx.x < 44) {
        int idx = blockIdx.x * 256 + tid;
        int j = idx & 7, lane = (idx >> 3) & 63, tile = idx >> 9;
        int n16 = lane & 15, kq = lane >> 4;
        float v;
        if (tile < 4) {
            int k = kq * 8 + j, n = tile * 16 + n16;
            v = (k < 8) ? load1(w1, k * 64 + n, isbf) * (0.35355339059327373f * 1.4426950408889634f) : 0.0f;
        } else if (tile < 12) {
            int t = (tile - 4) >> 1, kt = (tile - 4) & 1;
            int k = kt * 32 + kq * 8 + j, n = t * 16 + n16;
            v = load1(w2, k * 64 + n, isbf) * 0.125f;
        } else if (tile < 20) {
            int t = (tile - 12) >> 1, kt = (tile - 12) & 1;
            int k = kt * 32 + kq * 8 + j, n = t * 16 + n16;
            v = load1(w3, k * 64 + n, isbf) * 0.125f;
        } else {
            int kt = tile - 20;
            int k = kt * 32 + kq * 8 + j, n = n16;
            v = load1(w4, k * 16 + n, isbf) * (0.125f * 0.6931471805599453f);
        }
        Bws[idx] = fb2s(v);
    }
    // --- zero the edge accumulator ---
    if (tid < NB) {
        long n = n0 + tid;
        if (n < n_nodes) acc[n] = 0.0f;
    }
    if (n0 >= n_nodes) return;   // pure-prepack block (grid = max(nblk,44))

    // --- stage node_feats ---
    for (int i = tid; i < 512; i += 256) {
        W0L[(i >> 6) * 68 + (i & 63)] = load1(W0, i, isbf);
        W1L[(i >> 6) * 68 + (i & 63)] = load1(W1, i, isbf);
    }
    if (isbf) {
        for (int i = tid; i < NB * 32; i += 256) {
            int node = i >> 5, c8 = (i & 31) * 8;
            long ng = n0 + node; if (ng > n_nodes - 1) ng = n_nodes - 1;
            uint4 v = *(const uint4*)((const unsigned short*)nf + ng * 256 + c8);
            float f[8];
            f[0]=bf2f(v.x&0xffffu); f[1]=bf2f(v.x>>16);
            f[2]=bf2f(v.y&0xffffu); f[3]=bf2f(v.y>>16);
            f[4]=bf2f(v.z&0xffffu); f[5]=bf2f(v.z>>16);
            f[6]=bf2f(v.w&0xffffu); f[7]=bf2f(v.w>>16);
            #pragma unroll
            for (int t = 0; t < 8; t++) {
                int col = c8 + t;
                if (col < 64) Nd0[node * 68 + col] = f[t];
                else {
                    int cc = col - 64, vv = cc / 3, kk = cc - vv * 3;
                    Nd1[(kk * NB + node) * 68 + vv] = f[t];
                }
            }
        }
    } else {
        for (int i = tid; i < NB * 64; i += 256) {
            int node = i >> 6, c4 = (i & 63) * 4;
            long ng = n0 + node; if (ng > n_nodes - 1) ng = n_nodes - 1;
            float4 v = *(const float4*)((const float*)nf + ng * 256 + c4);
            float f[4] = {v.x, v.y, v.z, v.w};
            #pragma unroll
            for (int t = 0; t < 4; t++) {
                int col = c4 + t;
                if (col < 64) Nd0[node * 68 + col] = f[t];
                else {
                    int cc = col - 64, vv = cc / 3, kk = cc - vv * 3;
                    Nd1[(kk * NB + node) * 68 + vv] = f[t];
                }
            }
        }
    }
    __syncthreads();

    const int wv = tid >> 6, lane = tid & 63;
    const int u = lane & 7, ln = lane >> 3;
    float sum[4] = {0.0f, 0.0f, 0.0f, 0.0f};

    if (wv == 0) {
        const float* w = &W0L[u * 68];
        for (int v0 = 0; v0 < 64; v0 += 4) {
            float4 w4 = *(const float4*)(w + v0);
            #pragma unroll
            for (int j = 0; j < 4; j++) {
                float4 nd = *(const float4*)&Nd0[(ln + 8 * j) * 68 + v0];
                sum[j] += w4.x * nd.x + w4.y * nd.y + w4.z * nd.z + w4.w * nd.w;
            }
        }
        #pragma unroll
        for (int j = 0; j < 4; j++) {
            long node = n0 + ln + 8 * j;
            if (node < n_nodes) NA[node * 32 + u] = sum[j] * 0.03125f;
        }
    } else {
        const int kk = wv - 1;
        const float* w = &W1L[u * 68];
        const float* nd1 = &Nd1[kk * NB * 68];
        for (int v0 = 0; v0 < 64; v0 += 4) {
            float4 w4 = *(const float4*)(w + v0);
            #pragma unroll
            for (int j = 0; j < 4; j++) {
                float4 nd = *(const float4*)&nd1[(ln + 8 * j) * 68 + v0];
                sum[j] += w4.x * nd.x + w4.y * nd.y + w4.z * nd.z + w4.w * nd.w;
            }
        }
        #pragma unroll
        for (int j = 0; j < 4; j++) {
            long node = n0 + ln + 8 * j;
            if (node < n_nodes) NA[node * 32 + 8 + u * 3 + kk] = sum[j] * 0.018042195912175804f;
        }
    }
}

// ---------- MFMA edge kernel (operand-swapped: D = W^T @ H^T) ----------
// R2-proven structure (132.8 us) + exp2-fold silu. 32 edges/wave, W in LDS,
// H round-trip via LDS, TP epilogue via LDS with 2 lanes/edge.
// H layout: physical short idx = row*72 + ((col>>3) ^ ((row>>3)&1))*8 + (col&7)
//   row = edge-in-tile, col = feature.
// Read  (B-frag of H^T): lane(n16,kq) reads row=mt*16+n16, cols kt*32+kq*8..+7 -> b128.
// Write (D of Y^T):      lane(n16,kq) writes row=mt*16+n16, cols t*16+kq*4..+3 -> b64.
__global__ __launch_bounds__(256, 4) void k_edges_mfma(
    const void* __restrict__ ef, const void* __restrict__ ea, const void* __restrict__ qc,
    const int* __restrict__ eidx, const void* __restrict__ nf,
    const short* __restrict__ Bws, const float* __restrict__ NA,
    float* __restrict__ acc, int n_edges) {
    __shared__ __align__(16) short W[11264];
    __shared__ __align__(16) short Hs[4 * 2304];
    const int tid = threadIdx.x, lane = tid & 63, wv = tid >> 6;
    const int n16 = lane & 15, kq = lane >> 4;
    const int isbf = detect_bf16(nf);

    {
        const uint4* src = (const uint4*)Bws;
        uint4* dst = (uint4*)W;
        for (int i = tid; i < 1408; i += 256) dst[i] = src[i];
    }
    __syncthreads();

    short* Hw = Hs + wv * 2304;
    const int rbit = (n16 >> 3) & 1;                     // swizzle bit (shared by reads+writes)
    const int wrow = n16 * 72 + ((kq & 1) << 2);         // per-lane write base within a tile row
    const f32x4 zero = {0.0f, 0.0f, 0.0f, 0.0f};

    for (int half = 0; half < 2; half++) {
        const long E0 = (long)blockIdx.x * 256 + half * 128 + wv * 32;

        // ---- epilogue gathers, phase 1: issue edge-indexed loads now ----
        const int el = lane >> 1, h = lane & 1;
        const long e_ep = E0 + el;
        long ec = e_ep; if (ec > n_edges - 1) ec = n_edges - 1;
        const int s_nd = eidx[ec];
        const int r_nd = eidx[(long)n_edges + ec];
        float eav[4];
        load4(ea, ec * 4, isbf, eav);

        // ---- layer-1 B operand: edge_feats^T fragments ----
        short8 a1[2];
        #pragma unroll
        for (int nt = 0; nt < 2; nt++) {
            short8 a = {0,0,0,0,0,0,0,0};
            if (kq == 0) {
                long e = E0 + nt * 16 + n16;
                if (e > n_edges - 1) e = n_edges - 1;
                if (isbf) {
                    a = *(const short8*)((const unsigned short*)ef + e * 8);
                } else {
                    const float* pe = (const float*)ef + e * 8;
                    float4 v0 = *(const float4*)pe, v1 = *(const float4*)(pe + 4);
                    a[0]=fb2s(v0.x); a[1]=fb2s(v0.y); a[2]=fb2s(v0.z); a[3]=fb2s(v0.w);
                    a[4]=fb2s(v1.x); a[5]=fb2s(v1.y); a[6]=fb2s(v1.z); a[7]=fb2s(v1.w);
                }
            }
            a1[nt] = a;
        }

        {   // layer 1: Y^T[feat][edge] = W1^T @ X^T   (scales folded into W1 prepack)
            f32x4 c1[2][4];
            #pragma unroll
            for (int t = 0; t < 4; t++) {
                short8 b = *(const short8*)(W + t * 512 + lane * 8);
                #pragma unroll
                for (int nt = 0; nt < 2; nt++)
                    c1[nt][t] = __builtin_amdgcn_mfma_f32_16x16x32_bf16(b, a1[nt], zero, 0, 0, 0);
            }
            #pragma unroll
            for (int nt = 0; nt < 2; nt++)
                #pragma unroll
                for (int t = 0; t < 4; t++) {
                    uint2 pkd;
                    pkd.x = pack2(hsilu(c1[nt][t][0]), hsilu(c1[nt][t][1]));
                    pkd.y = pack2(hsilu(c1[nt][t][2]), hsilu(c1[nt][t][3]));
                    *(uint2*)(Hw + nt * 1152 + wrow + (((t * 2 + (kq >> 1)) ^ rbit) << 3)) = pkd;
                }
        }

        // ---- epilogue gathers, phase 2: node-indexed loads hide under layers 2-4 ----
        float q[4];
        load4(qc, (long)s_nd * 8 + h * 4, isbf, q);
        const float* nr = NA + (long)r_nd * 32;
        float4 n0 = *(const float4*)(nr + h * 4);
        float t12[12];
        *(float4*)(t12 + 0) = *(const float4*)(nr + 8 + h * 12);
        *(float4*)(t12 + 4) = *(const float4*)(nr + 12 + h * 12);
        *(float4*)(t12 + 8) = *(const float4*)(nr + 16 + h * 12);

        #pragma unroll
        for (int L = 0; L < 2; L++) {   // layers 2,3: Y^T = W^T(64x64) @ H^T
            const int base = (L == 0) ? 4 : 12;
            short8 aH[2][2];
            #pragma unroll
            for (int nt = 0; nt < 2; nt++)
                #pragma unroll
                for (int kt = 0; kt < 2; kt++)
                    aH[nt][kt] = *(const short8*)(Hw + nt * 1152 + n16 * 72 + (((kt * 4 + kq) ^ rbit) << 3));
            f32x4 c2[2][4];
            #pragma unroll
            for (int nt = 0; nt < 2; nt++)
                #pragma unroll
                for (int t = 0; t < 4; t++) c2[nt][t] = zero;
            #pragma unroll
            for (int kt = 0; kt < 2; kt++)
                #pragma unroll
                for (int t = 0; t < 4; t++) {
                    short8 b = *(const short8*)(W + (base + t * 2 + kt) * 512 + lane * 8);
                    #pragma unroll
                    for (int nt = 0; nt < 2; nt++)
                        c2[nt][t] = __builtin_amdgcn_mfma_f32_16x16x32_bf16(b, aH[nt][kt], c2[nt][t], 0, 0, 0);
                }
            #pragma unroll
            for (int nt = 0; nt < 2; nt++)
                #pragma unroll
                for (int t = 0; t < 4; t++) {
                    uint2 pkd;
                    pkd.x = pack2(hsilu(c2[nt][t][0]), hsilu(c2[nt][t][1]));
                    pkd.y = pack2(hsilu(c2[nt][t][2]), hsilu(c2[nt][t][3]));
                    *(uint2*)(Hw + nt * 1152 + wrow + (((t * 2 + (kq >> 1)) ^ rbit) << 3)) = pkd;
                }
        }

        float* TP = (float*)Hw;   // layer 4 output: 32 rows x stride 20 f32
        {
            short8 aH[2][2];
            #pragma unroll
            for (int nt = 0; nt < 2; nt++)
                #pragma unroll
                for (int kt = 0; kt < 2; kt++)
                    aH[nt][kt] = *(const short8*)(Hw + nt * 1152 + n16 * 72 + (((kt * 4 + kq) ^ rbit) << 3));
            f32x4 c4[2] = {zero, zero};
            #pragma unroll
            for (int kt = 0; kt < 2; kt++) {
                short8 b = *(const short8*)(W + (20 + kt) * 512 + lane * 8);
                #pragma unroll
                for (int nt = 0; nt < 2; nt++)
                    c4[nt] = __builtin_amdgcn_mfma_f32_16x16x32_bf16(b, aH[nt][kt], c4[nt], 0, 0, 0);
            }
            // lane holds edge = nt*16+n16, feats kq*4..kq*4+3 -> one b128 store per nt
            #pragma unroll
            for (int nt = 0; nt < 2; nt++)
                *(f32x4*)(TP + (nt * 16 + n16) * 20 + (kq << 2)) = c4[nt];
        }

        {   // epilogue: 2 lanes per edge, all operands preloaded
            float4 t0 = *(const float4*)(TP + el * 20 + h * 4);
            float4 t1 = *(const float4*)(TP + el * 20 + 8 + h * 4);
            float tp0[4] = {t0.x, t0.y, t0.z, t0.w};
            float tp1[4] = {t1.x, t1.y, t1.z, t1.w};
            float n0a[4] = {n0.x, n0.y, n0.z, n0.w};
            float p = 0.0f;
            #pragma unroll
            for (int i = 0; i < 4; i++) {
                float d = eav[1] * t12[i * 3] + eav[2] * t12[i * 3 + 1] + eav[3] * t12[i * 3 + 2];
                p += tp0[i] * q[i] * eav[0] * n0a[i] + tp1[i] * q[i] * d;
            }
            p += __shfl_xor(p, 1);
            if (h == 0 && e_ep < n_edges) atomicAdd(&acc[r_nd], p);
        }
    }
}

// ---------- accumulator -> output ----------
__global__ void k_out(const float* __restrict__ acc, void* __restrict__ out,
                      const void* __restrict__ nf, int n) {
    const int isbf = detect_bf16(nf);
    int i = blockIdx.x * 256 + threadIdx.x;
    if (i >= n) return;
    if (isbf) ((__hip_bfloat16*)out)[i] = __float2bfloat16(acc[i]);
    else      ((float*)out)[i] = acc[i];
}

// ---------- launch ----------
extern "C" void kernel_launch(void* const* d_in, const int* in_sizes, int n_in,
                              void* d_out, int out_size, void* d_ws, size_t ws_size,
                              hipStream_t stream) {
    const void* node_feats      = d_in[0];
    const void* charges_induced = d_in[2];
    const void* edge_feats      = d_in[3];
    const void* edge_attrs      = d_in[4];
    const void* mlp_w1          = d_in[6];
    const void* mlp_w2          = d_in[7];
    const void* mlp_w3          = d_in[8];
    const void* mlp_w4          = d_in[9];
    const void* W0              = d_in[10];
    const void* W1              = d_in[11];
    const int*  edge_index      = (const int*)d_in[12];

    const int n_nodes = in_sizes[0] / 256;
    const int n_edges = in_sizes[3] / 8;

    short* Bws = (short*)d_ws;                                 // 11264 shorts
    float* NA  = (float*)((char*)d_ws + 22528);                // n_nodes*32 f32
    float* acc = NA + (size_t)n_nodes * 32;                    // n_nodes f32

    int nblk = (n_nodes + NB - 1) / NB;
    if (nblk < 44) nblk = 44;
    k_node<<<nblk, 256, 0, stream>>>(node_feats, W0, W1,
        mlp_w1, mlp_w2, mlp_w3, mlp_w4, Bws, NA, acc, n_nodes);
    k_edges_mfma<<<(n_edges + 255) / 256, 256, 0, stream>>>(
        edge_feats, edge_attrs, charges_induced, edge_index, node_feats, Bws, NA, acc, n_edges);
    k_out<<<(n_nodes + 255) / 256, 256, 0, stream>>>(acc, d_out, node_feats, n_nodes);
}